// Round 8
// baseline (252.365 us; speedup 1.0000x reference)
//
#include <hip/hip_runtime.h>
#include <hip/hip_bf16.h>
#include <math.h>

typedef __bf16 bf16;
typedef __bf16 bf16x8 __attribute__((ext_vector_type(8)));
typedef float  f32x4  __attribute__((ext_vector_type(4)));
typedef float  f32x16 __attribute__((ext_vector_type(16)));
typedef unsigned u32x4 __attribute__((ext_vector_type(4)));

#define MFMA16(a,b,c) __builtin_amdgcn_mfma_f32_16x16x32_bf16((a),(b),(c),0,0,0)
#define MFMA32(a,b,c) __builtin_amdgcn_mfma_f32_32x32x16_bf16((a),(b),(c),0,0,0)
/* k is pre-scaled by 1/sqrt(512)*log2(e) in the projection epilogue,
   so attention uses exp2 directly. */
#define KSCALE 0.0637587159f

__device__ __forceinline__ void async16p(const void* g, void* l) {
    __builtin_amdgcn_global_load_lds((const __attribute__((address_space(1))) void*)g,
                                     (__attribute__((address_space(3))) void*)l,
                                     16, 0, 0);
}

__device__ __forceinline__ float fexp2(float x) {
#if __has_builtin(__builtin_amdgcn_exp2f)
    return __builtin_amdgcn_exp2f(x);
#else
    return exp2f(x);
#endif
}

__device__ __forceinline__ unsigned pkbf(float a, float b) {
    union { bf16 h[2]; unsigned u; } x;
    x.h[0] = (bf16)a; x.h[1] = (bf16)b; return x.u;
}

__device__ __forceinline__ void plswap(unsigned &a, unsigned &b) {
#if __has_builtin(__builtin_amdgcn_permlane32_swap)
    auto r = __builtin_amdgcn_permlane32_swap((int)a, (int)b, false, false);
    a = (unsigned)r[0]; b = (unsigned)r[1];
#else
    unsigned sa = (unsigned)__shfl_xor((int)a, 32);
    unsigned sb = (unsigned)__shfl_xor((int)b, 32);
    bool hi = (threadIdx.x & 32) != 0;
    unsigned na = hi ? sb : a;
    unsigned nb = hi ? b  : sa;
    a = na; b = nb;
#endif
}

// -------- prep: transpose 4 weights fp32[k][n] -> bf16 T[n][k]; ------------
// for Wo additionally accumulate colsum(Wo) into csum via atomics (csum
// zeroed by hipMemsetAsync).  (r6/r7: validated.)
__global__ __launch_bounds__(256) void prep_w_kernel(
    const float* __restrict__ Wq, const float* __restrict__ Wk,
    const float* __restrict__ Wv, const float* __restrict__ Wo,
    bf16* __restrict__ WqT, bf16* __restrict__ WkT,
    bf16* __restrict__ WvT, bf16* __restrict__ WoT,
    float* __restrict__ csum)
{
    __shared__ float tile[32][33];
    const int bx = blockIdx.x;
    const float* W; bf16* T;
    switch (bx >> 8) {
      case 0: W=Wq; T=WqT; break;
      case 1: W=Wk; T=WkT; break;
      case 2: W=Wv; T=WvT; break;
      default: W=Wo; T=WoT; break;
    }
    const int rest = bx & 255;
    const int k0 = (rest & 15) * 32, n0 = (rest >> 4) * 32;
    const int tx = threadIdx.x & 31, ty = threadIdx.x >> 5;
    float sacc = 0.f;
    #pragma unroll
    for (int i=0;i<32;i+=8) {
        float v = W[(size_t)(k0+ty+i)*512 + n0+tx];
        tile[ty+i][tx] = v;
        sacc += v;
    }
    __syncthreads();
    #pragma unroll
    for (int i=0;i<32;i+=8)
        T[(size_t)(n0+ty+i)*512 + k0+tx] = (bf16)tile[tx][ty+i];
    if ((bx >> 8) == 3) {           // Wo: column partial sums -> csum
        __syncthreads();            // transpose reads of tile done
        tile[ty][tx] = sacc;        // partial over k = ty+{0,8,16,24}
        __syncthreads();
        if (ty == 0) {
            float s = 0.f;
            #pragma unroll
            for (int j=0;j<8;j++) s += tile[j][tx];
            atomicAdd(&csum[n0+tx], s);
        }
    }
}

// ------------- fused projection GEMM: one staged A-tile -> TWO outputs -----
// (round-3/5/7 measured-best structure, 58-60 us: 64 KB dbuf LDS, vmcnt(8).
//  r4 (A-to-reg) and r6 (B-direct) both regressed; keep frozen.)
__global__ __launch_bounds__(256, 2) void gemm_proj_kernel(
    const float* __restrict__ Qf, const float* __restrict__ Kf,
    const bf16* __restrict__ WqT, const bf16* __restrict__ WkT,
    const bf16* __restrict__ WvT,
    const float* __restrict__ bq, const float* __restrict__ bk,
    const float* __restrict__ bv,
    bf16* __restrict__ qbb, bf16* __restrict__ kbb, bf16* __restrict__ vT)
{
    __shared__ __align__(16) char smem[65536];
    float* As32 = (float*)smem;            // [buf][128][32] fp32 (2x16 KB)
    bf16*  Bs   = (bf16*)(smem + 32768);   // [buf][p][128][32] bf16 (2x16 KB)
    bf16*  Lt   = (bf16*)smem;             // epilogue overlay (buf0 region)

    const int x = blockIdx.x;
    const bool isQ = (x < 256);
    int m0, n0;
    const float* A; const bf16 *BT0, *BT1; const float *bb0, *bb1;
    if (isQ) {
        m0 = (x >> 1) * 128; n0 = (x & 1) * 128;
        A = Qf; BT0 = WqT + (size_t)n0*512; BT1 = WqT + (size_t)(n0+256)*512;
        bb0 = bq + n0; bb1 = bq + n0 + 256;
    } else {
        int r = x - 256;
        m0 = (r >> 2) * 128; n0 = (r & 3) * 128;
        A = Kf; BT0 = WkT + (size_t)n0*512; BT1 = WvT + (size_t)n0*512;
        bb0 = bk + n0; bb1 = bv + n0;
    }

    const int tid = threadIdx.x;
    const int lane = tid & 63, wave = tid >> 6;
    const int qd = lane >> 4, lr = lane & 15;
    const int wm = (wave & 1) * 64, wn = (wave >> 1) * 64;

    const float* gA = A + (size_t)(m0 + (tid>>3))*512 + (((tid&7)^((tid>>3)&7))*4);
    const int bgr = ((tid & 3) ^ ((tid >> 3) & 3)) * 8;   // key (row>>1)&3
    const bf16* gB0 = BT0 + (size_t)(tid>>2)*512 + bgr;
    const bf16* gB1 = BT1 + (size_t)(tid>>2)*512 + bgr;

    f32x4 acc[2][4][4];
    #pragma unroll
    for (int p=0;p<2;p++)
      #pragma unroll
      for (int i=0;i<4;i++)
        #pragma unroll
        for (int j=0;j<4;j++) acc[p][i][j] = (f32x4){0,0,0,0};

    auto stage = [&](int buf, int k0) {
        float* lA = As32 + buf*4096 + wave*256;
        #pragma unroll
        for (int i=0;i<4;i++)
            async16p(gA + k0 + (size_t)i*32*512, lA + i*1024);
        bf16* lB0 = Bs + buf*8192 + wave*512;
        async16p(gB0 + k0,                  lB0);
        async16p(gB0 + k0 + (size_t)64*512, lB0 + 2048);
        bf16* lB1 = Bs + buf*8192 + 4096 + wave*512;
        async16p(gB1 + k0,                  lB1);
        async16p(gB1 + k0 + (size_t)64*512, lB1 + 2048);
    };

    stage(0, 0);
    for (int t = 0; t < 16; ++t) {
        const int cur = t & 1;
        __builtin_amdgcn_sched_barrier(0);
        __builtin_amdgcn_s_barrier();
        if (t < 15) {
            stage(cur ^ 1, (t+1)*32);
            asm volatile("s_waitcnt vmcnt(8)" ::: "memory");
        } else {
            asm volatile("s_waitcnt vmcnt(0)" ::: "memory");
        }
        __builtin_amdgcn_s_barrier();

        const float* Ab = As32 + cur*4096;
        const bf16*  Bb = Bs   + cur*8192;
        bf16x8 af[4], bfr[2][4];
        #pragma unroll
        for (int mi=0;mi<4;mi++) {
            int row = wm + mi*16 + lr;
            f32x4 f0 = *(f32x4*)(Ab + row*32 + (((qd*2  )^(lr&7))*4));
            f32x4 f1 = *(f32x4*)(Ab + row*32 + (((qd*2+1)^(lr&7))*4));
            bf16x8 a;
            a[0]=(bf16)f0[0]; a[1]=(bf16)f0[1]; a[2]=(bf16)f0[2]; a[3]=(bf16)f0[3];
            a[4]=(bf16)f1[0]; a[5]=(bf16)f1[1]; a[6]=(bf16)f1[2]; a[7]=(bf16)f1[3];
            af[mi] = a;
        }
        #pragma unroll
        for (int p=0;p<2;p++)
          #pragma unroll
          for (int ni=0;ni<4;ni++)
            bfr[p][ni] = *(bf16x8*)(Bb + p*4096 + (wn+ni*16+lr)*32
                                       + ((qd^((lr>>1)&3))*8));
        #pragma unroll
        for (int p=0;p<2;p++)
          #pragma unroll
          for (int mi=0;mi<4;mi++)
            #pragma unroll
            for (int ni=0;ni<4;ni++)
              acc[p][mi][ni] = MFMA16(af[mi], bfr[p][ni], acc[p][mi][ni]);
    }

    if (isQ) {
        #pragma unroll
        for (int p=0;p<2;p++) {
            const float* bb = p ? bb1 : bb0;
            #pragma unroll
            for (int ni=0;ni<4;ni++) {
                int nl = wn + ni*16 + lr;
                int n = n0 + p*256 + nl;
                float bv0 = bb[nl];
                #pragma unroll
                for (int mi=0;mi<4;mi++) {
                    int mb = m0 + wm + mi*16 + qd*4;
                    #pragma unroll
                    for (int r=0;r<4;r++)
                        qbb[(size_t)(mb+r)*512 + n] = (bf16)(acc[p][mi][ni][r] + bv0);
                }
            }
        }
    } else {
        // k: scaled write
        #pragma unroll
        for (int ni=0;ni<4;ni++) {
            int nl = wn + ni*16 + lr;
            int n = n0 + nl;
            float bv0 = bb0[nl];
            #pragma unroll
            for (int mi=0;mi<4;mi++) {
                int mb = m0 + wm + mi*16 + qd*4;
                #pragma unroll
                for (int r=0;r<4;r++)
                    kbb[(size_t)(mb+r)*512 + n] = (bf16)((acc[0][mi][ni][r] + bv0)*KSCALE);
            }
        }
        // v: vT[b][h][d][tok] via swizzled LDS transpose (acc[1])
        const int b = m0 >> 10, tok0 = m0 & 1023;
        const int row = tid >> 2, ch = tid & 3;
        #pragma unroll
        for (int half = 0; half < 2; ++half) {
            __syncthreads();
            if ((wn >> 6) == half) {
                #pragma unroll
                for (int ni=0;ni<4;ni++) {
                    int nl = ni*16 + lr;
                    float bvv = bb1[half*64 + nl];
                    #pragma unroll
                    for (int mi=0;mi<4;mi++)
                      #pragma unroll
                      for (int r=0;r<4;r++) {
                        int col = wm + mi*16 + qd*4 + r;
                        Lt[nl*128 + ((((col>>3)^(nl&7))<<3) | (col&7))]
                            = (bf16)(acc[1][mi][ni][r] + bvv);
                      }
                }
            }
            __syncthreads();
            const int h = (n0 >> 6) + half;
            bf16* dst = vT + ((size_t)((b*8 + h)*64 + row))*1024 + tok0 + ch*32;
            #pragma unroll
            for (int s=0;s<4;s++) {
                int g = (ch*4 + s) ^ (row & 7);
                *(uint4*)(dst + s*8) = *(uint4*)(Lt + row*128 + g*8);
            }
        }
    }
}

// ---------------- attention: swapped-QK^T 32x32, in-register softmax -------
__global__ __launch_bounds__(256, 4) void attn_kernel(
    const bf16* __restrict__ qb, const bf16* __restrict__ kb,
    const bf16* __restrict__ vT, bf16* __restrict__ attnb)
{
    const int x = blockIdx.x;
    const int qt = x >> 7, h = x & 7, b = (x & 127) >> 3;
    const int tid = threadIdx.x, lane = tid & 63, wave = tid >> 6;
    const int l = lane & 31, hi = lane >> 5;
    const int q0w = qt*128 + wave*32;

    __shared__ __align__(16) bf16 kv[2][2][4096];  // [buf][K|V][64 x 64]
    __shared__ float ls[4][32];

    bf16x8 aq[4];
    {
        const bf16* qrow = qb + ((size_t)(b*1024 + q0w + l))*512 + h*64 + hi*8;
        #pragma unroll
        for (int st=0; st<4; ++st) aq[st] = *(const bf16x8*)(qrow + st*16);
    }

    // staging with key(row) = (row&7)^(row>>3): row = wave*8+srow (+32)
    const int srow = lane >> 3;                 // 0..7
    const int sgA  = (lane & 7) ^ srow ^ wave;  // pre-swizzled granule
    const int sgB  = sgA ^ 4;                   // rows +32: key ^= 4
    const bf16* kg0 = kb + ((size_t)(b*1024 + wave*8 + srow))*512      + h*64 + sgA*8;
    const bf16* kg1 = kb + ((size_t)(b*1024 + wave*8 + srow + 32))*512 + h*64 + sgB*8;
    const bf16* vg0 = vT + ((size_t)((b*8 + h)*64 + wave*8 + srow))*1024      + sgA*8;
    const bf16* vg1 = vT + ((size_t)((b*8 + h)*64 + wave*8 + srow + 32))*1024 + sgB*8;

    auto stage = [&](int buf, int t) {
        const size_t ko = (size_t)t*64*512;
        async16p(kg0 + ko,     &kv[buf][0][wave*512]);
        async16p(kg1 + ko,     &kv[buf][0][2048 + wave*512]);
        async16p(vg0 + t*64,   &kv[buf][1][wave*512]);
        async16p(vg1 + t*64,   &kv[buf][1][2048 + wave*512]);
    };

    f32x16 accO[2];
    accO[0] = (f32x16)0.f; accO[1] = (f32x16)0.f;
    float lsum = 0.f;
    const int kx = (l & 7) ^ (l >> 3);   // read-side lane key component

    stage(0, 0);
    for (int t=0; t<16; ++t) {
        const int cur = t & 1;
        __builtin_amdgcn_sched_barrier(0);
        __builtin_amdgcn_s_barrier();
        if (t < 15) {
            stage(cur ^ 1, t + 1);
            asm volatile("s_waitcnt vmcnt(4)" ::: "memory");
        } else {
            asm volatile("s_waitcnt vmcnt(0)" ::: "memory");
        }
        __builtin_amdgcn_s_barrier();

        const bf16* Ks = kv[cur][0];
        const bf16* Vs = kv[cur][1];

        u32x4 paf[4];
        #pragma unroll
        for (int kb2=0; kb2<2; ++kb2) {
            f32x16 sT = (f32x16)0.f;
            __builtin_amdgcn_s_setprio(1);
            #pragma unroll
            for (int st=0; st<4; ++st) {
                bf16x8 kf = *(const bf16x8*)(Ks + (kb2*32 + l)*64
                               + (((st*2 + hi) ^ kx ^ (kb2<<2))*8));
                sT = MFMA32(kf, aq[st], sT);
            }
            __builtin_amdgcn_s_setprio(0);
            unsigned u[8];
            #pragma unroll
            for (int m=0; m<8; ++m) {
                float e0 = fexp2(sT[2*m]);
                float e1 = fexp2(sT[2*m+1]);
                lsum += e0 + e1;
                u[m] = pkbf(e0, e1);
            }
            #pragma unroll
            for (int sb=0; sb<2; ++sb) {
                unsigned a0=u[4*sb], a1=u[4*sb+1], a2=u[4*sb+2], a3=u[4*sb+3];
                plswap(a0, a2);
                plswap(a1, a3);
                paf[kb2*2 + sb] = (u32x4){a0, a1, a2, a3};
            }
        }
        __builtin_amdgcn_s_setprio(1);
        #pragma unroll
        for (int db=0; db<2; ++db) {
            f32x16 a = accO[db];
            #pragma unroll
            for (int st=0; st<4; ++st) {
                bf16x8 vf = *(const bf16x8*)(Vs + (db*32 + l)*64
                               + (((st*2 + hi) ^ kx ^ (db<<2))*8));
                u32x4 pp = paf[st];
                bf16x8 pf = *(bf16x8*)&pp;
                a = MFMA32(pf, vf, a);
            }
            accO[db] = a;
        }
        __builtin_amdgcn_s_setprio(0);
    }

    lsum += __shfl_xor(lsum, 32);
    ls[wave][l] = lsum;
    __syncthreads();

    #pragma unroll
    for (int g=0; g<4; ++g) {
        f32x4 lv = *(const f32x4*)(&ls[wave][g*8 + hi*4]);
        f32x4 inv;
        #pragma unroll
        for (int i=0;i<4;i++) inv[i] = 1.f / lv[i];
        #pragma unroll
        for (int db=0; db<2; ++db) {
            #pragma unroll
            for (int i=0;i<4;i++) {
                int r = g*4 + i;
                int qrow = q0w + g*8 + hi*4 + i;
                size_t idx = ((size_t)(b*1024 + qrow))*512 + h*64 + db*32 + l;
                float o = accO[db][r] * inv[i] + (float)qb[idx];
                attnb[idx] = (bf16)o;
            }
        }
    }
}

// ------ gemm_o (FUSED ln0-stats + GEMM + gelu + residual + ln1 + out) ------
// Full-row tile 64x512, 512 threads (8 waves: 2m x 4n), BK=64, 8 phases,
// dbuf LDS (A 2x8 KB + B 2x64 KB = 144 KB dynamic), counted vmcnt(9).
// A-fragment pass accumulates ln0 row stats (r7-validated scheme).
// Epilogue: G = rstd0*(x@Wo) - rstd0*mu0*csum + bo; xv = LN0(x)+gelu(G)
// (rounded to bf16 in-register, matching the old xb numerics); ln1 stats
// reduced in-block (shfl over lr + 4-partial LDS exchange); out fp32 direct.
// Replaces gemm_o + ln1 + the 16MB xb round-trip + one launch gap.
__global__ __launch_bounds__(512, 2) void gemm_o_kernel(
    const bf16* __restrict__ attnb, const bf16* __restrict__ WoT,
    const float* __restrict__ bo, const float* __restrict__ csum,
    float* __restrict__ out)
{
    extern __shared__ char smem[];
    bf16* As = (bf16*)smem;             // [buf][64][64]  (2x8 KB)
    bf16* Bs = (bf16*)(smem + 16384);   // [buf][512][64] (2x64 KB)
    __shared__ float2 rs[64];           // ln0 (mu, rstd) per block row
    __shared__ float  ws1[4][64], ws2[4][64];  // ln1 partials per n-wave

    const int m0 = blockIdx.x * 64;
    const int tid = threadIdx.x;
    const int lane = tid & 63, wave = tid >> 6;
    const int qd = lane >> 4, lr = lane & 15;
    const int wm = (wave & 1) * 32, wn = (wave >> 1) * 128;

    // staging: row&7 == lane>>3 for both A and B -> swizzle key (l&7)^(l>>3)
    const int srow8 = lane >> 3;
    const int sg    = (lane & 7) ^ srow8;
    const bf16* gA = attnb + (size_t)(m0 + wave*8 + srow8)*512 + sg*8;
    const bf16* gB = WoT   + (size_t)(wave*64 + srow8)*512 + sg*8;

    f32x4 acc[2][8];
    #pragma unroll
    for (int i=0;i<2;i++)
      #pragma unroll
      for (int j=0;j<8;j++) acc[i][j] = (f32x4){0,0,0,0};
    float s1[2] = {0.f,0.f}, s2[2] = {0.f,0.f};

    auto stage = [&](int buf, int k0) {
        async16p(gA + k0, As + buf*4096 + wave*512);
        bf16* lB = Bs + buf*32768 + wave*4096;
        #pragma unroll
        for (int j=0;j<8;j++)
            async16p(gB + k0 + (size_t)j*8*512, lB + j*512);
    };

    stage(0, 0);
    for (int t = 0; t < 8; ++t) {
        const int cur = t & 1;
        __builtin_amdgcn_sched_barrier(0);
        __builtin_amdgcn_s_barrier();
        if (t < 7) {
            stage(cur ^ 1, (t+1)*64);
            asm volatile("s_waitcnt vmcnt(9)" ::: "memory");
        } else {
            asm volatile("s_waitcnt vmcnt(0)" ::: "memory");
        }
        __builtin_amdgcn_s_barrier();

        const bf16* Ab = As + cur*4096;
        const bf16* Bb = Bs + cur*32768;
        #pragma unroll
        for (int kk=0; kk<2; ++kk) {
            bf16x8 af[2];
            #pragma unroll
            for (int mi=0;mi<2;mi++) {
                int row = wm + mi*16 + lr;
                af[mi] = *(bf16x8*)(Ab + row*64 + (((kk*4+qd)^(lr&7))*8));
                #pragma unroll
                for (int j=0;j<8;j++) {
                    float v = (float)af[mi][j];
                    s1[mi] += v; s2[mi] += v*v;
                }
            }
            #pragma unroll
            for (int ni=0;ni<8;ni++) {
                int brow = wn + ni*16 + lr;
                bf16x8 bfr = *(bf16x8*)(Bb + brow*64 + (((kk*4+qd)^(lr&7))*8));
                #pragma unroll
                for (int mi=0;mi<2;mi++)
                    acc[mi][ni] = MFMA16(af[mi], bfr, acc[mi][ni]);
            }
        }
    }

    // ln0 stats: reduce across the 4 qd lanes (lane bits 4,5); publish rows
    #pragma unroll
    for (int mi=0;mi<2;mi++) {
        s1[mi] += __shfl_xor(s1[mi], 16); s2[mi] += __shfl_xor(s2[mi], 16);
        s1[mi] += __shfl_xor(s1[mi], 32); s2[mi] += __shfl_xor(s2[mi], 32);
    }
    __syncthreads();
    if (wave < 2 && qd == 0) {   // waves 0,1 cover rows 0..63 uniquely
        #pragma unroll
        for (int mi=0;mi<2;mi++) {
            float mu  = s1[mi] * (1.f/512.f);
            float var = s2[mi] * (1.f/512.f) - mu*mu;
            rs[wm + mi*16 + lr] = make_float2(mu, rsqrtf(var + 1e-5f));
        }
    }
    __syncthreads();

    float csn[8], bon[8];
    #pragma unroll
    for (int ni=0;ni<8;ni++) {
        int n = wn + ni*16 + lr;
        csn[ni] = csum[n];
        bon[ni] = bo[n];
    }

    // epilogue: xv = LN0(x) + gelu(G), bf16-rounded; accumulate ln1 stats
    unsigned xvp[2][8][2];
    float t1[2][4] = {{0,0,0,0},{0,0,0,0}}, t2[2][4] = {{0,0,0,0},{0,0,0,0}};
    #pragma unroll
    for (int mi=0;mi<2;mi++) {
        #pragma unroll
        for (int ni=0;ni<8;ni++) {
            float xq[4];
            #pragma unroll
            for (int r=0;r<4;r++) {
                int rl = wm + mi*16 + qd*4 + r;
                float2 st = rs[rl];
                float mu0 = st.x, rstd0 = st.y;
                int n = wn + ni*16 + lr;
                float g = rstd0*acc[mi][ni][r] - rstd0*mu0*csn[ni] + bon[ni];
                float gelu = 0.5f * g * (1.f + erff(g * 0.70710678118654752f));
                float lnx = ((float)attnb[(size_t)(m0+rl)*512 + n] - mu0) * rstd0;
                float xv = lnx + gelu;
                t1[mi][r] += xv; t2[mi][r] += xv*xv;
                xq[r] = xv;
            }
            xvp[mi][ni][0] = pkbf(xq[0], xq[1]);
            xvp[mi][ni][1] = pkbf(xq[2], xq[3]);
        }
    }

    // ln1 stats: reduce over lr (lane bits 0..3), publish per n-wave partial
    #pragma unroll
    for (int mi=0;mi<2;mi++)
      #pragma unroll
      for (int r=0;r<4;r++)
        #pragma unroll
        for (int off=1; off<16; off<<=1) {
            t1[mi][r] += __shfl_xor(t1[mi][r], off);
            t2[mi][r] += __shfl_xor(t2[mi][r], off);
        }
    if (lr == 0) {
        #pragma unroll
        for (int mi=0;mi<2;mi++)
          #pragma unroll
          for (int r=0;r<4;r++) {
            int rl = wm + mi*16 + qd*4 + r;
            ws1[wave>>1][rl] = t1[mi][r];
            ws2[wave>>1][rl] = t2[mi][r];
          }
    }
    __syncthreads();

    // finalize ln1 per row and write fp32 out
    #pragma unroll
    for (int mi=0;mi<2;mi++) {
        #pragma unroll
        for (int r=0;r<4;r++) {
            int rl = wm + mi*16 + qd*4 + r;
            float S1 = ws1[0][rl] + ws1[1][rl] + ws1[2][rl] + ws1[3][rl];
            float S2 = ws2[0][rl] + ws2[1][rl] + ws2[2][rl] + ws2[3][rl];
            float mu1  = S1 * (1.f/512.f);
            float var1 = S2 * (1.f/512.f) - mu1*mu1;
            float rstd1 = rsqrtf(var1 + 1e-5f);
            float* orow = out + (size_t)(m0+rl)*512;
            #pragma unroll
            for (int ni=0;ni<8;ni++) {
                union { unsigned u; bf16 h[2]; } w;
                w.u = xvp[mi][ni][r>>1];
                float xv = (float)w.h[r&1];
                orow[wn + ni*16 + lr] = (xv - mu1) * rstd1;
            }
        }
    }
}

extern "C" void kernel_launch(void* const* d_in, const int* in_sizes, int n_in,
                              void* d_out, int out_size, void* d_ws, size_t ws_size,
                              hipStream_t stream)
{
    (void)in_sizes; (void)n_in; (void)out_size; (void)ws_size;
    const float* Q  = (const float*)d_in[0];
    const float* K  = (const float*)d_in[1];
    const float* Wq = (const float*)d_in[2];
    const float* bq = (const float*)d_in[3];
    const float* Wk = (const float*)d_in[4];
    const float* bk = (const float*)d_in[5];
    const float* Wv = (const float*)d_in[6];
    const float* bv = (const float*)d_in[7];
    const float* Wo = (const float*)d_in[8];
    const float* bo = (const float*)d_in[9];
    float* out = (float*)d_out;

    const size_t nTok = (size_t)16*1024*512;
    char* p = (char*)d_ws;
    auto alloc = [&](size_t bytes)->char* {
        char* r = p; p += (bytes + 255) & ~(size_t)255; return r;
    };
    bf16*   WqT   = (bf16*)alloc(512*512*2);
    bf16*   WkT   = (bf16*)alloc(512*512*2);
    bf16*   WvT   = (bf16*)alloc(512*512*2);
    bf16*   WoT   = (bf16*)alloc(512*512*2);
    bf16*   qbb   = (bf16*)alloc(nTok*2);
    bf16*   kbb   = (bf16*)alloc(nTok*2);
    bf16*   vT    = (bf16*)alloc(nTok*2);
    bf16*   attnb = (bf16*)alloc(nTok*2);
    float*  csum  = (float*)alloc(512*4);

    static bool attrSet = false;
    if (!attrSet) {
        hipFuncSetAttribute((const void*)gemm_o_kernel,
                            hipFuncAttributeMaxDynamicSharedMemorySize, 147456);
        attrSet = true;
    }

    hipMemsetAsync(csum, 0, 512*sizeof(float), stream);
    prep_w_kernel<<<1024, 256, 0, stream>>>(Wq, Wk, Wv, Wo, WqT, WkT, WvT, WoT, csum);
    gemm_proj_kernel<<<768, 256, 0, stream>>>(Q, K, WqT, WkT, WvT,
                                              bq, bk, bv, qbb, kbb, vT);
    attn_kernel<<<dim3(1024), 256, 0, stream>>>(qbb, kbb, vT, attnb);
    gemm_o_kernel<<<256, 512, 147456, stream>>>(attnb, WoT, bo, csum, out);
}

// Round 9
// 243.504 us; speedup vs baseline: 1.0364x; 1.0364x over previous
//
#include <hip/hip_runtime.h>
#include <hip/hip_bf16.h>
#include <math.h>

typedef __bf16 bf16;
typedef __bf16 bf16x8 __attribute__((ext_vector_type(8)));
typedef float  f32x4  __attribute__((ext_vector_type(4)));
typedef float  f32x16 __attribute__((ext_vector_type(16)));
typedef unsigned u32x4 __attribute__((ext_vector_type(4)));

#define MFMA16(a,b,c) __builtin_amdgcn_mfma_f32_16x16x32_bf16((a),(b),(c),0,0,0)
#define MFMA32(a,b,c) __builtin_amdgcn_mfma_f32_32x32x16_bf16((a),(b),(c),0,0,0)
/* k is pre-scaled by 1/sqrt(512)*log2(e) in the projection epilogue,
   so attention uses exp2 directly. */
#define KSCALE 0.0637587159f

__device__ __forceinline__ void async16p(const void* g, void* l) {
    __builtin_amdgcn_global_load_lds((const __attribute__((address_space(1))) void*)g,
                                     (__attribute__((address_space(3))) void*)l,
                                     16, 0, 0);
}

__device__ __forceinline__ float fexp2(float x) {
#if __has_builtin(__builtin_amdgcn_exp2f)
    return __builtin_amdgcn_exp2f(x);
#else
    return exp2f(x);
#endif
}

__device__ __forceinline__ unsigned pkbf(float a, float b) {
    union { bf16 h[2]; unsigned u; } x;
    x.h[0] = (bf16)a; x.h[1] = (bf16)b; return x.u;
}

__device__ __forceinline__ void plswap(unsigned &a, unsigned &b) {
#if __has_builtin(__builtin_amdgcn_permlane32_swap)
    auto r = __builtin_amdgcn_permlane32_swap((int)a, (int)b, false, false);
    a = (unsigned)r[0]; b = (unsigned)r[1];
#else
    unsigned sa = (unsigned)__shfl_xor((int)a, 32);
    unsigned sb = (unsigned)__shfl_xor((int)b, 32);
    bool hi = (threadIdx.x & 32) != 0;
    unsigned na = hi ? sb : a;
    unsigned nb = hi ? b  : sa;
    a = na; b = nb;
#endif
}

// -------- prep: transpose 4 weights fp32[k][n] -> bf16 T[n][k]; ------------
// for Wo additionally accumulate colsum(Wo) into csum via atomics (csum
// zeroed by hipMemsetAsync).  (r6/r7: validated.)
__global__ __launch_bounds__(256) void prep_w_kernel(
    const float* __restrict__ Wq, const float* __restrict__ Wk,
    const float* __restrict__ Wv, const float* __restrict__ Wo,
    bf16* __restrict__ WqT, bf16* __restrict__ WkT,
    bf16* __restrict__ WvT, bf16* __restrict__ WoT,
    float* __restrict__ csum)
{
    __shared__ float tile[32][33];
    const int bx = blockIdx.x;
    const float* W; bf16* T;
    switch (bx >> 8) {
      case 0: W=Wq; T=WqT; break;
      case 1: W=Wk; T=WkT; break;
      case 2: W=Wv; T=WvT; break;
      default: W=Wo; T=WoT; break;
    }
    const int rest = bx & 255;
    const int k0 = (rest & 15) * 32, n0 = (rest >> 4) * 32;
    const int tx = threadIdx.x & 31, ty = threadIdx.x >> 5;
    float sacc = 0.f;
    #pragma unroll
    for (int i=0;i<32;i+=8) {
        float v = W[(size_t)(k0+ty+i)*512 + n0+tx];
        tile[ty+i][tx] = v;
        sacc += v;
    }
    __syncthreads();
    #pragma unroll
    for (int i=0;i<32;i+=8)
        T[(size_t)(n0+ty+i)*512 + k0+tx] = (bf16)tile[tx][ty+i];
    if ((bx >> 8) == 3) {           // Wo: column partial sums -> csum
        __syncthreads();            // transpose reads of tile done
        tile[ty][tx] = sacc;        // partial over k = ty+{0,8,16,24}
        __syncthreads();
        if (ty == 0) {
            float s = 0.f;
            #pragma unroll
            for (int j=0;j<8;j++) s += tile[j][tx];
            atomicAdd(&csum[n0+tx], s);
        }
    }
}

// ------------- fused projection GEMM: one staged A-tile -> TWO outputs -----
// (round-3/5/7 measured-best structure, 58-60 us: 64 KB dbuf LDS, vmcnt(8).
//  r4 (A-to-reg) and r6 (B-direct) both regressed; structure frozen.)
// NEW (r9, T1): XCD co-location of A-tile sharers.  Blocks sharing a
// Q-tile (2) / K-tile (4) get ids differing by multiples of 8, so with the
// round-robin id%8 -> XCD mapping they land on the SAME XCD L2 and the
// shared 256 KB A-tile is fetched once per XCD instead of 2-4x.
__global__ __launch_bounds__(256, 2) void gemm_proj_kernel(
    const float* __restrict__ Qf, const float* __restrict__ Kf,
    const bf16* __restrict__ WqT, const bf16* __restrict__ WkT,
    const bf16* __restrict__ WvT,
    const float* __restrict__ bq, const float* __restrict__ bk,
    const float* __restrict__ bv,
    bf16* __restrict__ qbb, bf16* __restrict__ kbb, bf16* __restrict__ vT)
{
    __shared__ __align__(16) char smem[65536];
    float* As32 = (float*)smem;            // [buf][128][32] fp32 (2x16 KB)
    bf16*  Bs   = (bf16*)(smem + 32768);   // [buf][p][128][32] bf16 (2x16 KB)
    bf16*  Lt   = (bf16*)smem;             // epilogue overlay (buf0 region)

    const int x = blockIdx.x;
    const bool isQ = (x < 256);
    int m0, n0;
    const float* A; const bf16 *BT0, *BT1; const float *bb0, *bb1;
    if (isQ) {
        // sharers (same m, n=0/1) are 8 ids apart -> same XCD
        const int n = (x >> 3) & 1;
        const int m = (x & 7) | ((x >> 4) << 3);
        m0 = m * 128; n0 = n * 128;
        A = Qf; BT0 = WqT + (size_t)n0*512; BT1 = WqT + (size_t)(n0+256)*512;
        bb0 = bq + n0; bb1 = bq + n0 + 256;
    } else {
        // sharers (same m, n=0..3) are 8/16/24 ids apart -> same XCD
        const int r = x - 256;
        const int n = (r >> 3) & 3;
        const int m = (r & 7) | ((r >> 5) << 3);
        m0 = m * 128; n0 = n * 128;
        A = Kf; BT0 = WkT + (size_t)n0*512; BT1 = WvT + (size_t)n0*512;
        bb0 = bk + n0; bb1 = bv + n0;
    }

    const int tid = threadIdx.x;
    const int lane = tid & 63, wave = tid >> 6;
    const int qd = lane >> 4, lr = lane & 15;
    const int wm = (wave & 1) * 64, wn = (wave >> 1) * 64;

    const float* gA = A + (size_t)(m0 + (tid>>3))*512 + (((tid&7)^((tid>>3)&7))*4);
    const int bgr = ((tid & 3) ^ ((tid >> 3) & 3)) * 8;   // key (row>>1)&3
    const bf16* gB0 = BT0 + (size_t)(tid>>2)*512 + bgr;
    const bf16* gB1 = BT1 + (size_t)(tid>>2)*512 + bgr;

    f32x4 acc[2][4][4];
    #pragma unroll
    for (int p=0;p<2;p++)
      #pragma unroll
      for (int i=0;i<4;i++)
        #pragma unroll
        for (int j=0;j<4;j++) acc[p][i][j] = (f32x4){0,0,0,0};

    auto stage = [&](int buf, int k0) {
        float* lA = As32 + buf*4096 + wave*256;
        #pragma unroll
        for (int i=0;i<4;i++)
            async16p(gA + k0 + (size_t)i*32*512, lA + i*1024);
        bf16* lB0 = Bs + buf*8192 + wave*512;
        async16p(gB0 + k0,                  lB0);
        async16p(gB0 + k0 + (size_t)64*512, lB0 + 2048);
        bf16* lB1 = Bs + buf*8192 + 4096 + wave*512;
        async16p(gB1 + k0,                  lB1);
        async16p(gB1 + k0 + (size_t)64*512, lB1 + 2048);
    };

    stage(0, 0);
    for (int t = 0; t < 16; ++t) {
        const int cur = t & 1;
        __builtin_amdgcn_sched_barrier(0);
        __builtin_amdgcn_s_barrier();
        if (t < 15) {
            stage(cur ^ 1, (t+1)*32);
            asm volatile("s_waitcnt vmcnt(8)" ::: "memory");
        } else {
            asm volatile("s_waitcnt vmcnt(0)" ::: "memory");
        }
        __builtin_amdgcn_s_barrier();

        const float* Ab = As32 + cur*4096;
        const bf16*  Bb = Bs   + cur*8192;
        bf16x8 af[4], bfr[2][4];
        #pragma unroll
        for (int mi=0;mi<4;mi++) {
            int row = wm + mi*16 + lr;
            f32x4 f0 = *(f32x4*)(Ab + row*32 + (((qd*2  )^(lr&7))*4));
            f32x4 f1 = *(f32x4*)(Ab + row*32 + (((qd*2+1)^(lr&7))*4));
            bf16x8 a;
            a[0]=(bf16)f0[0]; a[1]=(bf16)f0[1]; a[2]=(bf16)f0[2]; a[3]=(bf16)f0[3];
            a[4]=(bf16)f1[0]; a[5]=(bf16)f1[1]; a[6]=(bf16)f1[2]; a[7]=(bf16)f1[3];
            af[mi] = a;
        }
        #pragma unroll
        for (int p=0;p<2;p++)
          #pragma unroll
          for (int ni=0;ni<4;ni++)
            bfr[p][ni] = *(bf16x8*)(Bb + p*4096 + (wn+ni*16+lr)*32
                                       + ((qd^((lr>>1)&3))*8));
        #pragma unroll
        for (int p=0;p<2;p++)
          #pragma unroll
          for (int mi=0;mi<4;mi++)
            #pragma unroll
            for (int ni=0;ni<4;ni++)
              acc[p][mi][ni] = MFMA16(af[mi], bfr[p][ni], acc[p][mi][ni]);
    }

    if (isQ) {
        #pragma unroll
        for (int p=0;p<2;p++) {
            const float* bb = p ? bb1 : bb0;
            #pragma unroll
            for (int ni=0;ni<4;ni++) {
                int nl = wn + ni*16 + lr;
                int n = n0 + p*256 + nl;
                float bv0 = bb[nl];
                #pragma unroll
                for (int mi=0;mi<4;mi++) {
                    int mb = m0 + wm + mi*16 + qd*4;
                    #pragma unroll
                    for (int r=0;r<4;r++)
                        qbb[(size_t)(mb+r)*512 + n] = (bf16)(acc[p][mi][ni][r] + bv0);
                }
            }
        }
    } else {
        // k: scaled write
        #pragma unroll
        for (int ni=0;ni<4;ni++) {
            int nl = wn + ni*16 + lr;
            int n = n0 + nl;
            float bv0 = bb0[nl];
            #pragma unroll
            for (int mi=0;mi<4;mi++) {
                int mb = m0 + wm + mi*16 + qd*4;
                #pragma unroll
                for (int r=0;r<4;r++)
                    kbb[(size_t)(mb+r)*512 + n] = (bf16)((acc[0][mi][ni][r] + bv0)*KSCALE);
            }
        }
        // v: vT[b][h][d][tok] via swizzled LDS transpose (acc[1])
        const int b = m0 >> 10, tok0 = m0 & 1023;
        const int row = tid >> 2, ch = tid & 3;
        #pragma unroll
        for (int half = 0; half < 2; ++half) {
            __syncthreads();
            if ((wn >> 6) == half) {
                #pragma unroll
                for (int ni=0;ni<4;ni++) {
                    int nl = ni*16 + lr;
                    float bvv = bb1[half*64 + nl];
                    #pragma unroll
                    for (int mi=0;mi<4;mi++)
                      #pragma unroll
                      for (int r=0;r<4;r++) {
                        int col = wm + mi*16 + qd*4 + r;
                        Lt[nl*128 + ((((col>>3)^(nl&7))<<3) | (col&7))]
                            = (bf16)(acc[1][mi][ni][r] + bvv);
                      }
                }
            }
            __syncthreads();
            const int h = (n0 >> 6) + half;
            bf16* dst = vT + ((size_t)((b*8 + h)*64 + row))*1024 + tok0 + ch*32;
            #pragma unroll
            for (int s=0;s<4;s++) {
                int g = (ch*4 + s) ^ (row & 7);
                *(uint4*)(dst + s*8) = *(uint4*)(Lt + row*128 + g*8);
            }
        }
    }
}

// ---------------- attention: swapped-QK^T 32x32, in-register softmax -------
__global__ __launch_bounds__(256, 4) void attn_kernel(
    const bf16* __restrict__ qb, const bf16* __restrict__ kb,
    const bf16* __restrict__ vT, bf16* __restrict__ attnb)
{
    const int x = blockIdx.x;
    const int qt = x >> 7, h = x & 7, b = (x & 127) >> 3;
    const int tid = threadIdx.x, lane = tid & 63, wave = tid >> 6;
    const int l = lane & 31, hi = lane >> 5;
    const int q0w = qt*128 + wave*32;

    __shared__ __align__(16) bf16 kv[2][2][4096];  // [buf][K|V][64 x 64]
    __shared__ float ls[4][32];

    bf16x8 aq[4];
    {
        const bf16* qrow = qb + ((size_t)(b*1024 + q0w + l))*512 + h*64 + hi*8;
        #pragma unroll
        for (int st=0; st<4; ++st) aq[st] = *(const bf16x8*)(qrow + st*16);
    }

    // staging with key(row) = (row&7)^(row>>3): row = wave*8+srow (+32)
    const int srow = lane >> 3;                 // 0..7
    const int sgA  = (lane & 7) ^ srow ^ wave;  // pre-swizzled granule
    const int sgB  = sgA ^ 4;                   // rows +32: key ^= 4
    const bf16* kg0 = kb + ((size_t)(b*1024 + wave*8 + srow))*512      + h*64 + sgA*8;
    const bf16* kg1 = kb + ((size_t)(b*1024 + wave*8 + srow + 32))*512 + h*64 + sgB*8;
    const bf16* vg0 = vT + ((size_t)((b*8 + h)*64 + wave*8 + srow))*1024      + sgA*8;
    const bf16* vg1 = vT + ((size_t)((b*8 + h)*64 + wave*8 + srow + 32))*1024 + sgB*8;

    auto stage = [&](int buf, int t) {
        const size_t ko = (size_t)t*64*512;
        async16p(kg0 + ko,     &kv[buf][0][wave*512]);
        async16p(kg1 + ko,     &kv[buf][0][2048 + wave*512]);
        async16p(vg0 + t*64,   &kv[buf][1][wave*512]);
        async16p(vg1 + t*64,   &kv[buf][1][2048 + wave*512]);
    };

    f32x16 accO[2];
    accO[0] = (f32x16)0.f; accO[1] = (f32x16)0.f;
    float lsum = 0.f;
    const int kx = (l & 7) ^ (l >> 3);   // read-side lane key component

    stage(0, 0);
    for (int t=0; t<16; ++t) {
        const int cur = t & 1;
        __builtin_amdgcn_sched_barrier(0);
        __builtin_amdgcn_s_barrier();
        if (t < 15) {
            stage(cur ^ 1, t + 1);
            asm volatile("s_waitcnt vmcnt(4)" ::: "memory");
        } else {
            asm volatile("s_waitcnt vmcnt(0)" ::: "memory");
        }
        __builtin_amdgcn_s_barrier();

        const bf16* Ks = kv[cur][0];
        const bf16* Vs = kv[cur][1];

        u32x4 paf[4];
        #pragma unroll
        for (int kb2=0; kb2<2; ++kb2) {
            f32x16 sT = (f32x16)0.f;
            __builtin_amdgcn_s_setprio(1);
            #pragma unroll
            for (int st=0; st<4; ++st) {
                bf16x8 kf = *(const bf16x8*)(Ks + (kb2*32 + l)*64
                               + (((st*2 + hi) ^ kx ^ (kb2<<2))*8));
                sT = MFMA32(kf, aq[st], sT);
            }
            __builtin_amdgcn_s_setprio(0);
            unsigned u[8];
            #pragma unroll
            for (int m=0; m<8; ++m) {
                float e0 = fexp2(sT[2*m]);
                float e1 = fexp2(sT[2*m+1]);
                lsum += e0 + e1;
                u[m] = pkbf(e0, e1);
            }
            #pragma unroll
            for (int sb=0; sb<2; ++sb) {
                unsigned a0=u[4*sb], a1=u[4*sb+1], a2=u[4*sb+2], a3=u[4*sb+3];
                plswap(a0, a2);
                plswap(a1, a3);
                paf[kb2*2 + sb] = (u32x4){a0, a1, a2, a3};
            }
        }
        __builtin_amdgcn_s_setprio(1);
        #pragma unroll
        for (int db=0; db<2; ++db) {
            f32x16 a = accO[db];
            #pragma unroll
            for (int st=0; st<4; ++st) {
                bf16x8 vf = *(const bf16x8*)(Vs + (db*32 + l)*64
                               + (((st*2 + hi) ^ kx ^ (db<<2))*8));
                u32x4 pp = paf[st];
                bf16x8 pf = *(bf16x8*)&pp;
                a = MFMA32(pf, vf, a);
            }
            accO[db] = a;
        }
        __builtin_amdgcn_s_setprio(0);
    }

    lsum += __shfl_xor(lsum, 32);
    ls[wave][l] = lsum;
    __syncthreads();

    #pragma unroll
    for (int g=0; g<4; ++g) {
        f32x4 lv = *(const f32x4*)(&ls[wave][g*8 + hi*4]);
        f32x4 inv;
        #pragma unroll
        for (int i=0;i<4;i++) inv[i] = 1.f / lv[i];
        #pragma unroll
        for (int db=0; db<2; ++db) {
            #pragma unroll
            for (int i=0;i<4;i++) {
                int r = g*4 + i;
                int qrow = q0w + g*8 + hi*4 + i;
                size_t idx = ((size_t)(b*1024 + qrow))*512 + h*64 + db*32 + l;
                float o = accO[db][r] * inv[i] + (float)qb[idx];
                attnb[idx] = (bf16)o;
            }
        }
    }
}

// ------- gemm_o: RAW attnb in, LN commuted; row-stats FUSED in K-loop ------
// (r7-measured pair with ln1 kept separate; r8's 144 KB mega-fusion cut
//  occupancy to 1 block/CU and regressed — do not repeat.)
__global__ __launch_bounds__(256, 4) void gemm_o_kernel(
    const bf16* __restrict__ attnb, const bf16* __restrict__ WoT,
    const float* __restrict__ bo, const float* __restrict__ csum,
    bf16* __restrict__ xb)
{
    __shared__ __align__(16) char smem[24576];
    __shared__ float2 rs[64];          // per-block-row (mu, rstd)
    bf16* As = (bf16*)smem;            // [buf][64][32]  (2x4 KB)
    bf16* Bs = (bf16*)(smem + 8192);   // [buf][128][32] (2x8 KB)
    const int m0 = blockIdx.x * 64, n0 = blockIdx.y * 128;
    const int tid = threadIdx.x;
    const int lane = tid & 63, wave = tid >> 6;
    const int qd = lane >> 4, lr = lane & 15;
    const int wm = (wave & 1) * 32, wn = (wave >> 1) * 64;

    const int bgr = ((tid & 3) ^ ((tid >> 3) & 3)) * 8;   // key (row>>1)&3
    const bf16* gA = attnb + (size_t)(m0 + (tid>>2))*512 + bgr;
    const bf16* gB = WoT   + (size_t)(n0 + (tid>>2))*512 + bgr;

    f32x4 acc[2][4];
    #pragma unroll
    for (int i=0;i<2;i++)
      #pragma unroll
      for (int j=0;j<4;j++) acc[i][j] = (f32x4){0,0,0,0};
    float s1[2] = {0.f, 0.f}, s2[2] = {0.f, 0.f};

    auto stage = [&](int buf, int k0) {
        async16p(gA + k0,                  As + buf*2048 + wave*512);
        bf16* lB = Bs + buf*4096 + wave*512;
        async16p(gB + k0,                  lB);
        async16p(gB + k0 + (size_t)64*512, lB + 2048);
    };

    stage(0, 0);
    for (int t = 0; t < 16; ++t) {
        const int cur = t & 1;
        __builtin_amdgcn_sched_barrier(0);
        __builtin_amdgcn_s_barrier();
        if (t < 15) {
            stage(cur ^ 1, (t+1)*32);
            asm volatile("s_waitcnt vmcnt(3)" ::: "memory");
        } else {
            asm volatile("s_waitcnt vmcnt(0)" ::: "memory");
        }
        __builtin_amdgcn_s_barrier();

        const bf16* Ab = As + cur*2048;
        const bf16* Bb = Bs + cur*4096;
        bf16x8 af[2], bfr[4];
        #pragma unroll
        for (int mi=0;mi<2;mi++) {
            af[mi] = *(bf16x8*)(Ab + (wm+mi*16+lr)*32 + ((qd^((lr>>1)&3))*8));
            #pragma unroll
            for (int j=0;j<8;j++) {
                float v = (float)af[mi][j];
                s1[mi] += v;
                s2[mi] += v*v;
            }
        }
        #pragma unroll
        for (int ni=0;ni<4;ni++)
            bfr[ni] = *(bf16x8*)(Bb + (wn+ni*16+lr)*32 + ((qd^((lr>>1)&3))*8));
        #pragma unroll
        for (int mi=0;mi<2;mi++)
          #pragma unroll
          for (int ni=0;ni<4;ni++)
            acc[mi][ni] = MFMA16(af[mi], bfr[ni], acc[mi][ni]);
    }

    // finish row stats: reduce across the 4 qd lanes (lane bits 4 and 5)
    #pragma unroll
    for (int mi=0;mi<2;mi++) {
        s1[mi] += __shfl_xor(s1[mi], 16); s2[mi] += __shfl_xor(s2[mi], 16);
        s1[mi] += __shfl_xor(s1[mi], 32); s2[mi] += __shfl_xor(s2[mi], 32);
    }
    if (wave < 2 && qd == 0) {          // waves 0,1 cover rows 0..63 uniquely
        #pragma unroll
        for (int mi=0;mi<2;mi++) {
            float mu  = s1[mi] * (1.f/512.f);
            float var = s2[mi] * (1.f/512.f) - mu*mu;
            rs[wm + mi*16 + lr] = make_float2(mu, rsqrtf(var + 1e-5f));
        }
    }
    __syncthreads();

    float csn[4], bon[4];
    #pragma unroll
    for (int ni=0;ni<4;ni++) {
        int n = n0 + wn + ni*16 + lr;
        csn[ni] = csum[n];
        bon[ni] = bo[n];
    }
    #pragma unroll
    for (int mi=0;mi<2;mi++) {
        #pragma unroll
        for (int r=0;r<4;r++) {
            int rl = wm + mi*16 + qd*4 + r;
            int row = m0 + rl;
            float2 st = rs[rl];
            float mu = st.x, rstd = st.y;
            #pragma unroll
            for (int ni=0;ni<4;ni++) {
                int n = n0 + wn + ni*16 + lr;
                float g = rstd*acc[mi][ni][r] - rstd*mu*csn[ni] + bon[ni];
                float gelu = 0.5f * g * (1.f + erff(g * 0.70710678118654752f));
                size_t idx = (size_t)row*512 + n;
                float lnx = ((float)attnb[idx] - mu) * rstd;
                xb[idx] = (bf16)(lnx + gelu);
            }
        }
    }
}

// ---------------- ln1: out = LN(xb) ----------------
__global__ __launch_bounds__(256) void ln1_kernel(
    const bf16* __restrict__ xb, float* __restrict__ out)
{
    const int wave = threadIdx.x >> 6, lane = threadIdx.x & 63;
    const int row = blockIdx.x*4 + wave;
    const size_t base = (size_t)row*512 + lane*8;
    bf16x8 xv = *(const bf16x8*)(xb + base);
    float x[8];
    #pragma unroll
    for (int i=0;i<8;i++) x[i] = (float)xv[i];
    float s1 = 0.f, s2 = 0.f;
    #pragma unroll
    for (int i=0;i<8;i++){ s1 += x[i]; s2 += x[i]*x[i]; }
    #pragma unroll
    for (int off=1; off<64; off<<=1) { s1 += __shfl_xor(s1, off); s2 += __shfl_xor(s2, off); }
    float mu  = s1 * (1.f/512.f);
    float var = s2 * (1.f/512.f) - mu*mu;
    float rstd = rsqrtf(var + 1e-5f);
    float4 o0 = {(x[0]-mu)*rstd,(x[1]-mu)*rstd,(x[2]-mu)*rstd,(x[3]-mu)*rstd};
    float4 o1 = {(x[4]-mu)*rstd,(x[5]-mu)*rstd,(x[6]-mu)*rstd,(x[7]-mu)*rstd};
    *(float4*)(out + base)     = o0;
    *(float4*)(out + base + 4) = o1;
}

extern "C" void kernel_launch(void* const* d_in, const int* in_sizes, int n_in,
                              void* d_out, int out_size, void* d_ws, size_t ws_size,
                              hipStream_t stream)
{
    (void)in_sizes; (void)n_in; (void)out_size; (void)ws_size;
    const float* Q  = (const float*)d_in[0];
    const float* K  = (const float*)d_in[1];
    const float* Wq = (const float*)d_in[2];
    const float* bq = (const float*)d_in[3];
    const float* Wk = (const float*)d_in[4];
    const float* bk = (const float*)d_in[5];
    const float* Wv = (const float*)d_in[6];
    const float* bv = (const float*)d_in[7];
    const float* Wo = (const float*)d_in[8];
    const float* bo = (const float*)d_in[9];
    float* out = (float*)d_out;

    const size_t nTok = (size_t)16*1024*512;
    char* p = (char*)d_ws;
    auto alloc = [&](size_t bytes)->char* {
        char* r = p; p += (bytes + 255) & ~(size_t)255; return r;
    };
    bf16*   WqT   = (bf16*)alloc(512*512*2);
    bf16*   WkT   = (bf16*)alloc(512*512*2);
    bf16*   WvT   = (bf16*)alloc(512*512*2);
    bf16*   WoT   = (bf16*)alloc(512*512*2);
    bf16*   qbb   = (bf16*)alloc(nTok*2);
    bf16*   kbb   = (bf16*)alloc(nTok*2);
    bf16*   vT    = (bf16*)alloc(nTok*2);
    bf16*   attnb = (bf16*)alloc(nTok*2);
    bf16*   xb    = (bf16*)alloc(nTok*2);
    float*  csum  = (float*)alloc(512*4);

    hipMemsetAsync(csum, 0, 512*sizeof(float), stream);
    prep_w_kernel<<<1024, 256, 0, stream>>>(Wq, Wk, Wv, Wo, WqT, WkT, WvT, WoT, csum);
    gemm_proj_kernel<<<768, 256, 0, stream>>>(Q, K, WqT, WkT, WvT,
                                              bq, bk, bv, qbb, kbb, vT);
    attn_kernel<<<dim3(1024), 256, 0, stream>>>(qbb, kbb, vT, attnb);
    gemm_o_kernel<<<dim3(256,4), 256, 0, stream>>>(attnb, WoT, bo, csum, xb);
    ln1_kernel<<<4096, 256, 0, stream>>>(xb, out);
}